// Round 8
// baseline (234.597 us; speedup 1.0000x reference)
//
#include <hip/hip_runtime.h>
#include <hip/hip_bf16.h>

#define N_NODES 50000
#define NE      800000
#define DIN     128
#define DHID    128
#define DOUT    64
#define BN_EPS  1e-5f
#define SLOT    64      // padded CSR row capacity; P(Poisson(16)>64)~3e-18, guarded
#define NBUK    391     // dest buckets of 128 nodes (c>>7)
#define BCAP    2560    // bucket capacity: mean 2046, sigma~45, +11 sigma, guarded
#define EPB     2048    // edges per block, binA
#define NPART   32      // partial copies of BN stats (atomic contention spreading)
#define LDW     132     // padded W1T row (66 dwords, %32==2 -> <=2-way LDS aliasing)
#define LDW2    132
#define G1_BLOCKS ((N_NODES + 63) / 64)   // 782

typedef __hip_bfloat16 bf16;
typedef short bf16x8 __attribute__((ext_vector_type(8)));
typedef float f32x4 __attribute__((ext_vector_type(4)));

__device__ __forceinline__ float ldf(const void* p, int i, int isbf) {
    if (isbf) return __bfloat162float(((const bf16*)p)[i]);
    return ((const float*)p)[i];
}
__device__ __forceinline__ unsigned short f2b(float f) {
    bf16 h = __float2bfloat16(f);
    return *(unsigned short*)&h;
}
__device__ __forceinline__ float2 up2(unsigned int u) {
    return make_float2(__uint_as_float(u << 16), __uint_as_float(u & 0xffff0000u));
}
__device__ __forceinline__ unsigned int pk2(float a, float b) {
    return ((unsigned int)f2b(a)) | (((unsigned int)f2b(b)) << 16);
}

#define DETECT_ISBF(W1raw, tid, sdet, isbf_out)                                   \
    if ((tid) == 0) sdet = 0;                                                     \
    __syncthreads();                                                              \
    {                                                                             \
        unsigned int u_ = ((unsigned int)((const unsigned short*)(W1raw))[tid]) << 16; \
        float f_ = fabsf(__uint_as_float(u_));                                    \
        if (!isnan(f_) && !isinf(f_) && f_ > 1e4f) atomicOr(&sdet, 1);            \
    }                                                                             \
    __syncthreads();                                                              \
    const int isbf_out = !sdet;

// ---------- binA: decode + LDS counting-sort by dest bucket ----------
// 391 buckets of 128 nodes. Pack: [31:23]=bucket(9b), [22:16]=node-in-bucket(7b), [15:0]=src.
// Per-wave histograms (contention /4) + pair-per-thread shuffle scan over 391 entries.
__global__ __launch_bounds__(256) void k_binA(const void* eiraw, int* __restrict__ gcnt,
                                              unsigned int* __restrict__ bpk) {
    __shared__ int hist4[4][392];
    __shared__ int cur4[4][392];
    __shared__ int eofs[392], gbase[392];
    __shared__ int wsum[4];
    __shared__ unsigned int stg[EPB];
    __shared__ int sdet;
    int tid = threadIdx.x;
    int lane = tid & 63;
    int wv = tid >> 6;
    if (tid == 0) sdet = 0;
    #pragma unroll
    for (int w2 = 0; w2 < 4; ++w2)
        for (int i = tid; i < 392; i += 256) hist4[w2][i] = 0;
    __syncthreads();
    if (tid < 64 && ((const unsigned int*)eiraw)[2 * tid + 1] != 0u) atomicOr(&sdet, 1);
    __syncthreads();
    const int isll = !sdet;

    int e0 = blockIdx.x * EPB;
    int nE = NE - e0; if (nE > EPB) nE = EPB;
    int r[8], c[8];
    #pragma unroll
    for (int q = 0; q < 8; ++q) {
        int li = q * 256 + tid;
        if (li < nE) {
            int e = e0 + li;
            if (isll) { r[q] = (int)((const long long*)eiraw)[e]; c[q] = (int)((const long long*)eiraw)[NE + e]; }
            else      { r[q] = ((const int*)eiraw)[e];            c[q] = ((const int*)eiraw)[NE + e]; }
            atomicAdd(&hist4[wv][c[q] >> 7], 1);
        } else r[q] = -1;
    }
    __syncthreads();
    // pair-per-thread exclusive scan: thread t owns buckets 2t, 2t+1
    int b0 = 2 * tid, b1 = 2 * tid + 1;
    int h00 = 0, h01 = 0, h02 = 0, h03 = 0, h10 = 0, h11 = 0, h12 = 0, h13 = 0;
    if (b0 < 392) { h00 = hist4[0][b0]; h01 = hist4[1][b0]; h02 = hist4[2][b0]; h03 = hist4[3][b0]; }
    if (b1 < 392) { h10 = hist4[0][b1]; h11 = hist4[1][b1]; h12 = hist4[2][b1]; h13 = hist4[3][b1]; }
    int t0 = h00 + h01 + h02 + h03;
    int t1 = h10 + h11 + h12 + h13;
    int pair = t0 + t1;
    int inc = pair;
    #pragma unroll
    for (int off = 1; off < 64; off <<= 1) {
        int u = __shfl_up(inc, off, 64);
        if (lane >= off) inc += u;
    }
    if (lane == 63) wsum[wv] = inc;
    __syncthreads();
    int woff = 0;
    #pragma unroll
    for (int w2 = 0; w2 < 3; ++w2) if (w2 < wv) woff += wsum[w2];
    int ex = woff + inc - pair;
    if (b0 < 392) {
        eofs[b0] = ex;
        cur4[0][b0] = ex; cur4[1][b0] = ex + h00; cur4[2][b0] = ex + h00 + h01; cur4[3][b0] = ex + h00 + h01 + h02;
        if (b0 < NBUK) gbase[b0] = atomicAdd(&gcnt[b0], t0);
    }
    int ex1 = ex + t0;
    if (b1 < 392) {
        eofs[b1] = ex1;
        cur4[0][b1] = ex1; cur4[1][b1] = ex1 + h10; cur4[2][b1] = ex1 + h10 + h11; cur4[3][b1] = ex1 + h10 + h11 + h12;
        if (b1 < NBUK) gbase[b1] = atomicAdd(&gcnt[b1], t1);
    }
    __syncthreads();
    #pragma unroll
    for (int q = 0; q < 8; ++q) {
        if (r[q] >= 0) {
            int b = c[q] >> 7;
            int p = atomicAdd(&cur4[wv][b], 1);
            stg[p] = ((unsigned int)b << 23) | ((unsigned int)(c[q] & 127) << 16) | (unsigned int)r[q];
        }
    }
    __syncthreads();
    for (int i = tid; i < nE; i += 256) {
        unsigned int v = stg[i];
        int b = v >> 23;
        int pos = gbase[b] + (i - eofs[b]);
        if (pos < BCAP) bpk[(size_t)b * BCAP + pos] = v;
    }
}

// ---------- fat kernel: blocks [0,NBUK) run binB; blocks [NBUK, NBUK+G1_BLOCKS) run gemm1 ----------
// LDS union 19.5KB -> 8 blocks/CU -> all 1173 blocks co-resident (true overlap).
// binB: per-bucket (128 nodes) counting sort -> padded CSR (mult-of-16, dummy=N_NODES), counts+disv.
// gemm1: g1 = bf16(x@W1 + b1) UNSCALED, W1T staged in two 64-column halves (16.9KB at a time).
__global__ __launch_bounds__(256) void k_binB_gemm1(const unsigned int* __restrict__ bpk,
                                                    const int* __restrict__ gcnt,
                                                    int* __restrict__ counts, float* __restrict__ disv,
                                                    int* __restrict__ ej,
                                                    const void* __restrict__ x, const void* __restrict__ W1,
                                                    const void* __restrict__ b1,
                                                    unsigned short* __restrict__ g1) {
    __shared__ __align__(16) char smraw[19472];
    __shared__ int sdet;
    int tid = threadIdx.x;

    if (blockIdx.x < NBUK) {
        // ---------------- binB ----------------
        int (*cnt4)[256] = (int(*)[256])smraw;                    //  4096 B
        int (*cur4)[256] = (int(*)[256])(smraw + 4096);           //  4096 B
        int* eofs        = (int*)(smraw + 8192);                  //  1024 B
        int* wsum        = (int*)(smraw + 9216);                  //    16 B
        unsigned int* stg = (unsigned int*)(smraw + 9232);        // 10240 B (BCAP)

        int b = blockIdx.x;
        int lane = tid & 63;
        int wv = tid >> 6;
        int m = gcnt[b]; if (m > BCAP) m = BCAP;
        #pragma unroll
        for (int w2 = 0; w2 < 4; ++w2) cnt4[w2][tid] = 0;
        __syncthreads();
        const unsigned int* src = bpk + (size_t)b * BCAP;
        for (int i = tid; i < m; i += 256)
            atomicAdd(&cnt4[wv][(src[i] >> 16) & 127], 1);
        __syncthreads();
        int h0 = cnt4[0][tid], h1 = cnt4[1][tid], h2 = cnt4[2][tid], h3 = cnt4[3][tid];
        int hv = h0 + h1 + h2 + h3;     // zero for tid>=128
        int inc = hv;
        #pragma unroll
        for (int off = 1; off < 64; off <<= 1) {
            int u = __shfl_up(inc, off, 64);
            if (lane >= off) inc += u;
        }
        if (lane == 63) wsum[wv] = inc;
        __syncthreads();
        int woff = 0;
        #pragma unroll
        for (int w2 = 0; w2 < 3; ++w2) if (w2 < wv) woff += wsum[w2];
        int ex = woff + inc - hv;
        eofs[tid] = ex;
        cur4[0][tid] = ex;
        cur4[1][tid] = ex + h0;
        cur4[2][tid] = ex + h0 + h1;
        cur4[3][tid] = ex + h0 + h1 + h2;
        int c0 = b << 7;
        if (tid < 128) {
            int cg = c0 + tid;
            if (cg < N_NODES) {
                counts[cg] = hv;                   // single writer per node, true in-degree
                disv[cg] = rsqrtf((float)(hv + 1));
                int hc = hv < SLOT ? hv : SLOT;
                int hp = (hc + 15) & ~15; if (hp > SLOT) hp = SLOT;
                for (int k = hc; k < hp; ++k) ej[(size_t)cg * SLOT + k] = N_NODES;  // pad -> zero row
            } else if (cg == N_NODES) {
                disv[cg] = 0.f;                    // dummy-edge weight: exact zero
            }
        }
        __syncthreads();
        for (int i = tid; i < m; i += 256) {
            unsigned int v = src[i];
            int cl = (v >> 16) & 127;
            int p = atomicAdd(&cur4[wv][cl], 1);
            stg[p] = v & 0x007fffffu;          // keep [22:16]=node, [15:0]=src
        }
        __syncthreads();
        for (int i = tid; i < m; i += 256) {
            unsigned int v = stg[i];
            int cl = v >> 16;
            int k = i - eofs[cl];
            if (k < SLOT) ej[(size_t)(c0 + cl) * SLOT + k] = (int)(v & 0xffffu);
        }
    } else {
        // ---------------- gemm1 (unscaled, two half-stages of W1T) ----------------
        unsigned short* wt = (unsigned short*)smraw;              // 64*LDW bf16 = 16896 B
        DETECT_ISBF(W1, tid, sdet, isbf)

        int lane = tid & 63;
        int wave = tid >> 6;
        int bid = blockIdx.x - NBUK;
        int m0 = bid * 64 + wave * 16;
        int lm = lane & 15;
        int quad = lane >> 4;

        bf16x8 a[4];
        int arow = m0 + lm;
        int arow_c = arow < N_NODES ? arow : 0;
        if (isbf) {
            const unsigned short* xb = (const unsigned short*)x;
            #pragma unroll
            for (int q = 0; q < 4; ++q)
                a[q] = *(const bf16x8*)(xb + arow_c * DIN + q * 32 + quad * 8);
        } else {
            const float* xf = (const float*)x;
            #pragma unroll
            for (int q = 0; q < 4; ++q) {
                bf16x8 t;
                #pragma unroll
                for (int j = 0; j < 8; ++j)
                    t[j] = (short)f2b(xf[arow_c * DIN + q * 32 + quad * 8 + j]);
                a[q] = t;
            }
        }

        for (int half = 0; half < 2; ++half) {
            // stage 64 N-columns of W1T: wt[nloc*LDW + k] = W1[k][half*64+nloc]
            #pragma unroll 4
            for (int i = 0; i < 32; ++i) {
                int idx = i * 256 + tid;      // 0..8191
                int k = idx >> 6;             // 0..127
                int nloc = idx & 63;          // 0..63
                int gidx = k * DHID + half * 64 + nloc;
                wt[nloc * LDW + k] = isbf ? ((const unsigned short*)W1)[gidx]
                                          : f2b(((const float*)W1)[gidx]);
            }
            __syncthreads();

            #pragma unroll
            for (int ntl = 0; ntl < 4; ++ntl) {
                int n0 = half * 64 + ntl * 16;
                f32x4 acc = {0.f, 0.f, 0.f, 0.f};
                #pragma unroll
                for (int q = 0; q < 4; ++q) {
                    bf16x8 b = *(const bf16x8*)(wt + (ntl * 16 + lm) * LDW + q * 32 + quad * 8);
                    acc = __builtin_amdgcn_mfma_f32_16x16x32_bf16(a[q], b, acc, 0, 0, 0);
                }
                float bias = ldf(b1, n0 + lm, isbf);
                #pragma unroll
                for (int r = 0; r < 4; ++r) {
                    int grow = m0 + quad * 4 + r;
                    if (grow <= N_NODES) {
                        float val = (grow < N_NODES) ? (acc[r] + bias) : 0.f;  // row N -> exact zero
                        g1[grow * DHID + n0 + lm] = f2b(val);
                    }
                }
            }
            __syncthreads();
        }
    }
}

// ---------- propagate 1 + fused BN partial stats: 16-deep gather, per-source dis (scalar loads) ----------
// agg1[c] = bf16( dis[c] * (dis[c]*g1[c] + sum dis[s]*g1[s]) )
__global__ __launch_bounds__(256) void k_prop1(const int* __restrict__ counts, const float* __restrict__ disv,
                                               const int* __restrict__ ej,
                                               const unsigned int* __restrict__ g1p,   // [N+1][64] dwords
                                               unsigned int* __restrict__ agg1p,
                                               float* __restrict__ statsP) {
    __shared__ float sp[1024];
    int tid = threadIdx.x;
    int w = tid >> 6;
    int n = blockIdx.x * 4 + w;
    n = __builtin_amdgcn_readfirstlane(n);   // wave-uniform: scalarize edge addressing
    int lane = tid & 63;
    float ax = 0.f, ay = 0.f;
    if (n < N_NODES) {
        int cnt = counts[n];
        float dv = disv[n];
        int t = cnt < SLOT ? cnt : SLOT;
        int tp = (t + 15) & ~15; if (tp > SLOT) tp = SLOT;
        const int* ejn = ej + (size_t)n * SLOT;
        float2 v = up2(g1p[(size_t)n * 64 + lane]);
        float ax0 = dv * v.x, ay0 = dv * v.y, ax1 = 0.f, ay1 = 0.f;
        float ax2 = 0.f, ay2 = 0.f, ax3 = 0.f, ay3 = 0.f;
        for (int j = 0; j < tp; j += 16) {
            const int4* ej4 = (const int4*)(ejn + j);
            int4 E0 = ej4[0], E1 = ej4[1], E2 = ej4[2], E3 = ej4[3];
            int e[16] = {E0.x, E0.y, E0.z, E0.w, E1.x, E1.y, E1.z, E1.w,
                         E2.x, E2.y, E2.z, E2.w, E3.x, E3.y, E3.z, E3.w};
            unsigned int gg[16];
            float ds[16];
            #pragma unroll
            for (int q = 0; q < 16; ++q) { gg[q] = g1p[(size_t)e[q] * 64 + lane]; ds[q] = disv[e[q]]; }
            #pragma unroll
            for (int q = 0; q < 16; ++q) {
                float2 f = up2(gg[q]);
                if ((q & 3) == 0) { ax0 = fmaf(ds[q], f.x, ax0); ay0 = fmaf(ds[q], f.y, ay0); }
                else if ((q & 3) == 1) { ax1 = fmaf(ds[q], f.x, ax1); ay1 = fmaf(ds[q], f.y, ay1); }
                else if ((q & 3) == 2) { ax2 = fmaf(ds[q], f.x, ax2); ay2 = fmaf(ds[q], f.y, ay2); }
                else { ax3 = fmaf(ds[q], f.x, ax3); ay3 = fmaf(ds[q], f.y, ay3); }
            }
        }
        ax = dv * ((ax0 + ax1) + (ax2 + ax3));
        ay = dv * ((ay0 + ay1) + (ay2 + ay3));
        agg1p[(size_t)n * 64 + lane] = pk2(ax, ay);
    }
    // fused BN stats: per-wave values -> LDS -> one atomic per address per block
    sp[w * 256 + 2 * lane]       = ax;
    sp[w * 256 + 2 * lane + 1]   = ay;
    sp[w * 256 + 128 + 2 * lane] = ax * ax;
    sp[w * 256 + 129 + 2 * lane] = ay * ay;
    __syncthreads();
    float s = sp[tid] + sp[256 + tid] + sp[512 + tid] + sp[768 + tid];
    atomicAdd(&statsP[(blockIdx.x & (NPART - 1)) * 256 + tid], s);
}

// ---------- GEMM2 (MFMA), BN finalize from partials in preamble, BN+ReLU on A, dis-scale out ----------
__global__ __launch_bounds__(256) void k_gemm2_mfma(const unsigned int* __restrict__ agg1p,
                                                    const float* __restrict__ statsP,
                                                    const void* __restrict__ gamma, const void* __restrict__ beta,
                                                    const void* __restrict__ W2, const void* __restrict__ b2,
                                                    const void* __restrict__ W1, const int* __restrict__ counts,
                                                    unsigned short* __restrict__ g2) {
    __shared__ unsigned short w2t[64 * LDW2];
    __shared__ float sc[128], sh[128], redu[256];
    __shared__ int sdet;
    int tid = threadIdx.x;
    DETECT_ISBF(W1, tid, sdet, isbf)

    #pragma unroll 4
    for (int i = 0; i < 32; ++i) {
        int idx = i * 256 + tid;
        int k = idx >> 6, n = idx & 63;
        w2t[n * LDW2 + k] = isbf ? ((const unsigned short*)W2)[idx]
                                 : f2b(((const float*)W2)[idx]);
    }
    {
        float s = 0.f;
        #pragma unroll
        for (int p = 0; p < NPART; ++p) s += statsP[p * 256 + tid];
        redu[tid] = s;
    }
    __syncthreads();
    if (tid < 128) {
        const float invn = 1.0f / (float)N_NODES;
        float mu = redu[tid] * invn;
        float var = redu[128 + tid] * invn - mu * mu;
        float rs = rsqrtf(var + BN_EPS);
        float g = ldf(gamma, tid, isbf);
        sc[tid] = rs * g;
        sh[tid] = ldf(beta, tid, isbf) - mu * rs * g;
    }
    __syncthreads();

    int lane = tid & 63;
    int wave = tid >> 6;
    int m0 = blockIdx.x * 64 + wave * 16;
    int lm = lane & 15;
    int quad = lane >> 4;

    int arow = m0 + lm;
    int arow_c = arow < N_NODES ? arow : 0;
    bf16x8 a[4];
    #pragma unroll
    for (int q = 0; q < 4; ++q) {
        uint4 gv = *(const uint4*)(agg1p + (size_t)arow_c * 64 + q * 16 + quad * 4);
        int kb = q * 32 + quad * 8;
        float2 f0 = up2(gv.x), f1 = up2(gv.y), f2 = up2(gv.z), f3 = up2(gv.w);
        float e0 = f0.x * sc[kb + 0] + sh[kb + 0];
        float e1 = f0.y * sc[kb + 1] + sh[kb + 1];
        float e2 = f1.x * sc[kb + 2] + sh[kb + 2];
        float e3 = f1.y * sc[kb + 3] + sh[kb + 3];
        float e4 = f2.x * sc[kb + 4] + sh[kb + 4];
        float e5 = f2.y * sc[kb + 5] + sh[kb + 5];
        float e6 = f3.x * sc[kb + 6] + sh[kb + 6];
        float e7 = f3.y * sc[kb + 7] + sh[kb + 7];
        bf16x8 t;
        t[0] = (short)f2b(e0 > 0.f ? e0 : 0.f);
        t[1] = (short)f2b(e1 > 0.f ? e1 : 0.f);
        t[2] = (short)f2b(e2 > 0.f ? e2 : 0.f);
        t[3] = (short)f2b(e3 > 0.f ? e3 : 0.f);
        t[4] = (short)f2b(e4 > 0.f ? e4 : 0.f);
        t[5] = (short)f2b(e5 > 0.f ? e5 : 0.f);
        t[6] = (short)f2b(e6 > 0.f ? e6 : 0.f);
        t[7] = (short)f2b(e7 > 0.f ? e7 : 0.f);
        a[q] = t;
    }

    float dsc[4];
    #pragma unroll
    for (int r = 0; r < 4; ++r) {
        int grow = m0 + quad * 4 + r;
        dsc[r] = (grow < N_NODES) ? rsqrtf((float)(counts[grow] + 1)) : 0.f;
    }

    #pragma unroll
    for (int nt = 0; nt < 4; ++nt) {
        int n0 = nt * 16;
        f32x4 acc = {0.f, 0.f, 0.f, 0.f};
        #pragma unroll
        for (int q = 0; q < 4; ++q) {
            bf16x8 b = *(const bf16x8*)(w2t + (n0 + lm) * LDW2 + q * 32 + quad * 8);
            acc = __builtin_amdgcn_mfma_f32_16x16x32_bf16(a[q], b, acc, 0, 0, 0);
        }
        float bias = ldf(b2, n0 + lm, isbf);
        #pragma unroll
        for (int r = 0; r < 4; ++r) {
            int grow = m0 + quad * 4 + r;
            if (grow <= N_NODES)          // row N_NODES -> zero row for prop2 padding
                g2[grow * DOUT + n0 + lm] = f2b(dsc[r] * (acc[r] + bias));
        }
    }
}

// ---------- propagate 2 + log_softmax: 32 lanes/node, 2 feats/lane, 16-deep, no tails ----------
__global__ __launch_bounds__(256) void k_prop2_lsm(const int* __restrict__ counts, const int* __restrict__ ej,
                                                   const unsigned int* __restrict__ g2p,   // [N+1][32] dwords
                                                   const void* __restrict__ W1, void* __restrict__ out) {
    __shared__ int sdet;
    int tid = threadIdx.x;
    DETECT_ISBF(W1, tid, sdet, isbf)

    int n = blockIdx.x * 8 + (tid >> 5);
    if (n >= N_NODES) return;
    int lane = tid & 31;
    int cnt = counts[n];
    int t = cnt < SLOT ? cnt : SLOT;
    int tp = (t + 15) & ~15; if (tp > SLOT) tp = SLOT;
    const int* ejn = ej + (size_t)n * SLOT;
    float2 v = up2(g2p[(size_t)n * 32 + lane]);
    float ax0 = v.x, ay0 = v.y, ax1 = 0.f, ay1 = 0.f;
    float ax2 = 0.f, ay2 = 0.f, ax3 = 0.f, ay3 = 0.f;
    for (int j = 0; j < tp; j += 16) {
        const int4* ej4 = (const int4*)(ejn + j);
        int4 E0 = ej4[0], E1 = ej4[1], E2 = ej4[2], E3 = ej4[3];
        int e[16] = {E0.x, E0.y, E0.z, E0.w, E1.x, E1.y, E1.z, E1.w,
                     E2.x, E2.y, E2.z, E2.w, E3.x, E3.y, E3.z, E3.w};
        unsigned int gg[16];
        #pragma unroll
        for (int q = 0; q < 16; ++q) gg[q] = g2p[(size_t)e[q] * 32 + lane];
        #pragma unroll
        for (int q = 0; q < 16; ++q) {
            float2 f = up2(gg[q]);
            if ((q & 3) == 0) { ax0 += f.x; ay0 += f.y; }
            else if ((q & 3) == 1) { ax1 += f.x; ay1 += f.y; }
            else if ((q & 3) == 2) { ax2 += f.x; ay2 += f.y; }
            else { ax3 += f.x; ay3 += f.y; }
        }
    }
    float dv = rsqrtf((float)(cnt + 1));
    float ax = dv * ((ax0 + ax1) + (ax2 + ax3));
    float ay = dv * ((ay0 + ay1) + (ay2 + ay3));
    float m = fmaxf(ax, ay);
    #pragma unroll
    for (int off = 16; off >= 1; off >>= 1) m = fmaxf(m, __shfl_xor(m, off, 32));
    float sum = __expf(ax - m) + __expf(ay - m);
    #pragma unroll
    for (int off = 16; off >= 1; off >>= 1) sum += __shfl_xor(sum, off, 32);
    float lse = m + __logf(sum);
    float rx = ax - lse, ry = ay - lse;
    if (isbf) {
        ((unsigned int*)out)[(size_t)n * 32 + lane] = pk2(rx, ry);
    } else {
        float2* o = (float2*)((float*)out + (size_t)n * 64 + 2 * lane);
        *o = make_float2(rx, ry);
    }
}

extern "C" void kernel_launch(void* const* d_in, const int* in_sizes, int n_in,
                              void* d_out, int out_size, void* d_ws, size_t ws_size,
                              hipStream_t stream) {
    const void* x     = d_in[0];
    const void* W1    = d_in[1];
    const void* b1    = d_in[2];
    const void* gamma = d_in[3];
    const void* beta  = d_in[4];
    const void* W2    = d_in[5];
    const void* b2    = d_in[6];
    const void* ei    = d_in[7];

    char* w = (char*)d_ws;
    float*          statsP = (float*)(w + 0);                  //     32,768 (NPART*256*4)
    int*            gcnt   = (int*)(w + 32768);                //      2,048 (391 used)
    int*            counts = (int*)(w + 34816);                //    200,000
    float*          disv   = (float*)(w + 234816);             //    200,016 ((N+1) floats, padded)
    int*            ej     = (int*)(w + 434832);               // 12,800,000 (N*SLOT*4)
    unsigned int*   bpk    = (unsigned int*)(w + 13234832);    //  4,003,840 (NBUK*BCAP*4)
    unsigned short* g1     = (unsigned short*)(w + 17238672);  // 12,800,256 ((N+1)*128*2)
    unsigned int*   agg1p  = (unsigned int*)(w + 30038928);    // 12,800,000
    unsigned short* g2     = (unsigned short*)(w + 42838928);  //  6,400,128 ((N+1)*64*2)
    // total ~49.2 MB

    hipMemsetAsync(w, 0, 34816, stream);   // statsP + gcnt

    k_binA<<<(NE + EPB - 1) / EPB, 256, 0, stream>>>(ei, gcnt, bpk);

    k_binB_gemm1<<<NBUK + G1_BLOCKS, 256, 0, stream>>>(bpk, gcnt, counts, disv, ej, x, W1, b1, g1);

    k_prop1<<<(N_NODES + 3) / 4, 256, 0, stream>>>(counts, disv, ej, (const unsigned int*)g1, agg1p, statsP);

    k_gemm2_mfma<<<(N_NODES + 63) / 64, 256, 0, stream>>>(agg1p, statsP, gamma, beta, W2, b2,
                                                          W1, counts, g2);

    k_prop2_lsm<<<(N_NODES + 7) / 8, 256, 0, stream>>>(counts, ej, (const unsigned int*)g2, W1, d_out);
}

// Round 9
// 205.119 us; speedup vs baseline: 1.1437x; 1.1437x over previous
//
#include <hip/hip_runtime.h>
#include <hip/hip_bf16.h>

#define N_NODES 50000
#define NE      800000
#define DIN     128
#define DHID    128
#define DOUT    64
#define BN_EPS  1e-5f
#define SLOT    64      // padded CSR row capacity; P(Poisson(16)>64)~3e-18, guarded
#define NBUK    196     // dest buckets of 256 nodes (c>>8)
#define BCAP    4864    // bucket capacity: mean 4096, sigma~64, +12 sigma, guarded
#define BREG    19      // BCAP/256 register-cached entries per thread in binB
#define EPB     2048    // edges per block, binA
#define NPART   32      // partial copies of BN stats (atomic contention spreading)
#define LDW     132     // padded W1T row (66 dwords, %32==2 -> <=2-way LDS aliasing)
#define LDW2    132

typedef __hip_bfloat16 bf16;
typedef short bf16x8 __attribute__((ext_vector_type(8)));
typedef float f32x4 __attribute__((ext_vector_type(4)));

__device__ __forceinline__ float ldf(const void* p, int i, int isbf) {
    if (isbf) return __bfloat162float(((const bf16*)p)[i]);
    return ((const float*)p)[i];
}
__device__ __forceinline__ unsigned short f2b(float f) {
    bf16 h = __float2bfloat16(f);
    return *(unsigned short*)&h;
}
__device__ __forceinline__ float2 up2(unsigned int u) {
    return make_float2(__uint_as_float(u << 16), __uint_as_float(u & 0xffff0000u));
}
__device__ __forceinline__ unsigned int pk2(float a, float b) {
    return ((unsigned int)f2b(a)) | (((unsigned int)f2b(b)) << 16);
}

#define DETECT_ISBF(W1raw, tid, sdet, isbf_out)                                   \
    if ((tid) == 0) sdet = 0;                                                     \
    __syncthreads();                                                              \
    {                                                                             \
        unsigned int u_ = ((unsigned int)((const unsigned short*)(W1raw))[tid]) << 16; \
        float f_ = fabsf(__uint_as_float(u_));                                    \
        if (!isnan(f_) && !isinf(f_) && f_ > 1e4f) atomicOr(&sdet, 1);            \
    }                                                                             \
    __syncthreads();                                                              \
    const int isbf_out = !sdet;

// ---------- binA: decode + LDS counting-sort by dest bucket (r7/196-bucket version) ----------
__global__ __launch_bounds__(256) void k_binA(const void* eiraw, int* __restrict__ gcnt,
                                              unsigned int* __restrict__ bpk) {
    __shared__ int hist4[4][256];
    __shared__ int cur4[4][256];
    __shared__ int eofs[256], gbase[256];
    __shared__ int wsum[4];
    __shared__ unsigned int stg[EPB];
    __shared__ int sdet;
    int tid = threadIdx.x;
    int lane = tid & 63;
    int wv = tid >> 6;
    if (tid == 0) sdet = 0;
    #pragma unroll
    for (int w2 = 0; w2 < 4; ++w2) hist4[w2][tid] = 0;
    __syncthreads();
    if (tid < 64 && ((const unsigned int*)eiraw)[2 * tid + 1] != 0u) atomicOr(&sdet, 1);
    __syncthreads();
    const int isll = !sdet;

    int e0 = blockIdx.x * EPB;
    int nE = NE - e0; if (nE > EPB) nE = EPB;
    int r[8], c[8];
    #pragma unroll
    for (int q = 0; q < 8; ++q) {
        int li = q * 256 + tid;
        if (li < nE) {
            int e = e0 + li;
            if (isll) { r[q] = (int)((const long long*)eiraw)[e]; c[q] = (int)((const long long*)eiraw)[NE + e]; }
            else      { r[q] = ((const int*)eiraw)[e];            c[q] = ((const int*)eiraw)[NE + e]; }
            atomicAdd(&hist4[wv][c[q] >> 8], 1);
        } else r[q] = -1;
    }
    __syncthreads();
    int h0 = hist4[0][tid], h1 = hist4[1][tid], h2 = hist4[2][tid], h3 = hist4[3][tid];
    int tot = h0 + h1 + h2 + h3;
    int inc = tot;
    #pragma unroll
    for (int off = 1; off < 64; off <<= 1) {
        int u = __shfl_up(inc, off, 64);
        if (lane >= off) inc += u;
    }
    if (lane == 63) wsum[wv] = inc;
    __syncthreads();
    int woff = 0;
    #pragma unroll
    for (int w2 = 0; w2 < 3; ++w2) if (w2 < wv) woff += wsum[w2];
    int ex = woff + inc - tot;
    eofs[tid] = ex;
    cur4[0][tid] = ex;
    cur4[1][tid] = ex + h0;
    cur4[2][tid] = ex + h0 + h1;
    cur4[3][tid] = ex + h0 + h1 + h2;
    if (tid < NBUK) gbase[tid] = atomicAdd(&gcnt[tid], tot);
    __syncthreads();
    #pragma unroll
    for (int q = 0; q < 8; ++q) {
        if (r[q] >= 0) {
            int b = c[q] >> 8;
            int p = atomicAdd(&cur4[wv][b], 1);
            stg[p] = ((unsigned int)b << 24) | ((unsigned int)(c[q] & 255) << 16) | (unsigned int)r[q];
        }
    }
    __syncthreads();
    for (int i = tid; i < nE; i += 256) {
        unsigned int v = stg[i];
        int b = v >> 24;
        int pos = gbase[b] + (i - eofs[b]);
        if (pos < BCAP) bpk[(size_t)b * BCAP + pos] = v;
    }
}

// ---------- binB (separate dispatch): reg-cached single global pass, per-wave counters, shuffle scan ----------
// Pads each CSR row up to a multiple of 16 with dummy index N_NODES; writes counts + disv.
__global__ __launch_bounds__(256) void k_binB(const unsigned int* __restrict__ bpk, const int* __restrict__ gcnt,
                                              int* __restrict__ counts, float* __restrict__ disv,
                                              int* __restrict__ ej) {
    __shared__ int cnt4[4][256];
    __shared__ int cur4[4][256];
    __shared__ int eofs[256];
    __shared__ int wsum[4];
    __shared__ unsigned int stg[BCAP];
    int b = blockIdx.x;
    int tid = threadIdx.x;
    int lane = tid & 63;
    int wv = tid >> 6;
    int m = gcnt[b]; if (m > BCAP) m = BCAP;
    #pragma unroll
    for (int w2 = 0; w2 < 4; ++w2) cnt4[w2][tid] = 0;
    __syncthreads();
    const unsigned int* src = bpk + (size_t)b * BCAP;
    unsigned int vv[BREG];
    #pragma unroll
    for (int q = 0; q < BREG; ++q) {
        int i = q * 256 + tid;
        vv[q] = (i < m) ? src[i] : 0xffffffffu;
        if (vv[q] != 0xffffffffu) atomicAdd(&cnt4[wv][(vv[q] >> 16) & 255], 1);
    }
    __syncthreads();
    int h0 = cnt4[0][tid], h1 = cnt4[1][tid], h2 = cnt4[2][tid], h3 = cnt4[3][tid];
    int hv = h0 + h1 + h2 + h3;
    int inc = hv;
    #pragma unroll
    for (int off = 1; off < 64; off <<= 1) {
        int u = __shfl_up(inc, off, 64);
        if (lane >= off) inc += u;
    }
    if (lane == 63) wsum[wv] = inc;
    __syncthreads();
    int woff = 0;
    #pragma unroll
    for (int w2 = 0; w2 < 3; ++w2) if (w2 < wv) woff += wsum[w2];
    int ex = woff + inc - hv;
    eofs[tid] = ex;
    cur4[0][tid] = ex;
    cur4[1][tid] = ex + h0;
    cur4[2][tid] = ex + h0 + h1;
    cur4[3][tid] = ex + h0 + h1 + h2;
    int c0 = b << 8;
    int cg = c0 + tid;
    if (cg < N_NODES) {
        counts[cg] = hv;                   // single writer per node, true in-degree
        disv[cg] = rsqrtf((float)(hv + 1));
        int hc = hv < SLOT ? hv : SLOT;
        int hp = (hc + 15) & ~15; if (hp > SLOT) hp = SLOT;
        for (int k = hc; k < hp; ++k) ej[(size_t)cg * SLOT + k] = N_NODES;  // pad -> zero row
    } else if (cg == N_NODES) {
        disv[cg] = 0.f;                    // dummy-edge weight: exact zero
    }
    __syncthreads();
    #pragma unroll
    for (int q = 0; q < BREG; ++q) {
        if (vv[q] != 0xffffffffu) {
            int cl = (vv[q] >> 16) & 255;
            int p = atomicAdd(&cur4[wv][cl], 1);
            stg[p] = vv[q] & 0x00ffffffu;  // keep [23:16]=node, [15:0]=src
        }
    }
    __syncthreads();
    for (int i = tid; i < m; i += 256) {
        unsigned int v = stg[i];
        int cl = v >> 16;
        int k = i - eofs[cl];
        if (k < SLOT) ej[(size_t)(c0 + cl) * SLOT + k] = (int)(v & 0xffffu);
    }
}

// ---------- GEMM1 (separate): g1 = bf16(x@W1 + b1) UNSCALED; vectorized W1T staging; zero row N ----------
__global__ __launch_bounds__(256) void k_gemm1_mfma(const void* __restrict__ x, const void* __restrict__ W1,
                                                    const void* __restrict__ b1,
                                                    unsigned short* __restrict__ g1) {
    __shared__ unsigned short wt[128 * LDW];
    __shared__ int sdet;
    int tid = threadIdx.x;
    DETECT_ISBF(W1, tid, sdet, isbf)

    if (isbf) {
        // 16B/lane global loads: 8 iters x uint4 (8 ushorts), scatter to wt[n][k] transposed
        const unsigned short* wsrc = (const unsigned short*)W1;
        #pragma unroll
        for (int i = 0; i < 8; ++i) {
            int flat = i * 2048 + tid * 8;       // multiple of 8; k-major W1 [k][n]
            int k = flat >> 7, n = flat & 127;
            uint4 v = *(const uint4*)(wsrc + flat);
            wt[(n + 0) * LDW + k] = (unsigned short)(v.x & 0xffff);
            wt[(n + 1) * LDW + k] = (unsigned short)(v.x >> 16);
            wt[(n + 2) * LDW + k] = (unsigned short)(v.y & 0xffff);
            wt[(n + 3) * LDW + k] = (unsigned short)(v.y >> 16);
            wt[(n + 4) * LDW + k] = (unsigned short)(v.z & 0xffff);
            wt[(n + 5) * LDW + k] = (unsigned short)(v.z >> 16);
            wt[(n + 6) * LDW + k] = (unsigned short)(v.w & 0xffff);
            wt[(n + 7) * LDW + k] = (unsigned short)(v.w >> 16);
        }
    } else {
        #pragma unroll 4
        for (int i = 0; i < 64; ++i) {
            int idx = i * 256 + tid;
            int k = idx >> 7, n = idx & 127;
            wt[n * LDW + k] = f2b(((const float*)W1)[idx]);
        }
    }
    __syncthreads();

    int lane = tid & 63;
    int wave = tid >> 6;
    int m0 = blockIdx.x * 64 + wave * 16;
    int lm = lane & 15;
    int quad = lane >> 4;

    bf16x8 a[4];
    int arow = m0 + lm;
    int arow_c = arow < N_NODES ? arow : 0;
    if (isbf) {
        const unsigned short* xb = (const unsigned short*)x;
        #pragma unroll
        for (int q = 0; q < 4; ++q)
            a[q] = *(const bf16x8*)(xb + arow_c * DIN + q * 32 + quad * 8);
    } else {
        const float* xf = (const float*)x;
        #pragma unroll
        for (int q = 0; q < 4; ++q) {
            bf16x8 t;
            #pragma unroll
            for (int j = 0; j < 8; ++j)
                t[j] = (short)f2b(xf[arow_c * DIN + q * 32 + quad * 8 + j]);
            a[q] = t;
        }
    }

    #pragma unroll
    for (int nt = 0; nt < 8; ++nt) {
        int n0 = nt * 16;
        f32x4 acc = {0.f, 0.f, 0.f, 0.f};
        #pragma unroll
        for (int q = 0; q < 4; ++q) {
            bf16x8 b = *(const bf16x8*)(wt + (n0 + lm) * LDW + q * 32 + quad * 8);
            acc = __builtin_amdgcn_mfma_f32_16x16x32_bf16(a[q], b, acc, 0, 0, 0);
        }
        float bias = ldf(b1, n0 + lm, isbf);
        #pragma unroll
        for (int r = 0; r < 4; ++r) {
            int grow = m0 + quad * 4 + r;
            if (grow <= N_NODES) {
                float val = (grow < N_NODES) ? (acc[r] + bias) : 0.f;  // row N -> exact zero
                g1[grow * DHID + n0 + lm] = f2b(val);
            }
        }
    }
}

// ---------- propagate 1 + fused BN partial stats: 16-deep gather, per-source dis (scalar loads) ----------
// agg1[c] = bf16( dis[c] * (dis[c]*g1[c] + sum dis[s]*g1[s]) )
__global__ __launch_bounds__(256) void k_prop1(const int* __restrict__ counts, const float* __restrict__ disv,
                                               const int* __restrict__ ej,
                                               const unsigned int* __restrict__ g1p,   // [N+1][64] dwords
                                               unsigned int* __restrict__ agg1p,
                                               float* __restrict__ statsP) {
    __shared__ float sp[1024];
    int tid = threadIdx.x;
    int w = tid >> 6;
    int n = blockIdx.x * 4 + w;
    n = __builtin_amdgcn_readfirstlane(n);   // wave-uniform: scalarize edge addressing
    int lane = tid & 63;
    float ax = 0.f, ay = 0.f;
    if (n < N_NODES) {
        int cnt = counts[n];
        float dv = disv[n];
        int t = cnt < SLOT ? cnt : SLOT;
        int tp = (t + 15) & ~15; if (tp > SLOT) tp = SLOT;
        const int* ejn = ej + (size_t)n * SLOT;
        float2 v = up2(g1p[(size_t)n * 64 + lane]);
        float ax0 = dv * v.x, ay0 = dv * v.y, ax1 = 0.f, ay1 = 0.f;
        float ax2 = 0.f, ay2 = 0.f, ax3 = 0.f, ay3 = 0.f;
        for (int j = 0; j < tp; j += 16) {
            const int4* ej4 = (const int4*)(ejn + j);
            int4 E0 = ej4[0], E1 = ej4[1], E2 = ej4[2], E3 = ej4[3];
            int e[16] = {E0.x, E0.y, E0.z, E0.w, E1.x, E1.y, E1.z, E1.w,
                         E2.x, E2.y, E2.z, E2.w, E3.x, E3.y, E3.z, E3.w};
            unsigned int gg[16];
            float ds[16];
            #pragma unroll
            for (int q = 0; q < 16; ++q) { gg[q] = g1p[(size_t)e[q] * 64 + lane]; ds[q] = disv[e[q]]; }
            #pragma unroll
            for (int q = 0; q < 16; ++q) {
                float2 f = up2(gg[q]);
                if ((q & 3) == 0) { ax0 = fmaf(ds[q], f.x, ax0); ay0 = fmaf(ds[q], f.y, ay0); }
                else if ((q & 3) == 1) { ax1 = fmaf(ds[q], f.x, ax1); ay1 = fmaf(ds[q], f.y, ay1); }
                else if ((q & 3) == 2) { ax2 = fmaf(ds[q], f.x, ax2); ay2 = fmaf(ds[q], f.y, ay2); }
                else { ax3 = fmaf(ds[q], f.x, ax3); ay3 = fmaf(ds[q], f.y, ay3); }
            }
        }
        ax = dv * ((ax0 + ax1) + (ax2 + ax3));
        ay = dv * ((ay0 + ay1) + (ay2 + ay3));
        agg1p[(size_t)n * 64 + lane] = pk2(ax, ay);
    }
    // fused BN stats: per-wave values -> LDS -> one atomic per address per block
    sp[w * 256 + 2 * lane]       = ax;
    sp[w * 256 + 2 * lane + 1]   = ay;
    sp[w * 256 + 128 + 2 * lane] = ax * ax;
    sp[w * 256 + 129 + 2 * lane] = ay * ay;
    __syncthreads();
    float s = sp[tid] + sp[256 + tid] + sp[512 + tid] + sp[768 + tid];
    atomicAdd(&statsP[(blockIdx.x & (NPART - 1)) * 256 + tid], s);
}

// ---------- GEMM2 (MFMA), BN finalize from partials in preamble, BN+ReLU on A, dis-scale out ----------
__global__ __launch_bounds__(256) void k_gemm2_mfma(const unsigned int* __restrict__ agg1p,
                                                    const float* __restrict__ statsP,
                                                    const void* __restrict__ gamma, const void* __restrict__ beta,
                                                    const void* __restrict__ W2, const void* __restrict__ b2,
                                                    const void* __restrict__ W1, const int* __restrict__ counts,
                                                    unsigned short* __restrict__ g2) {
    __shared__ unsigned short w2t[64 * LDW2];
    __shared__ float sc[128], sh[128], redu[256];
    __shared__ int sdet;
    int tid = threadIdx.x;
    DETECT_ISBF(W1, tid, sdet, isbf)

    #pragma unroll 4
    for (int i = 0; i < 32; ++i) {
        int idx = i * 256 + tid;
        int k = idx >> 6, n = idx & 63;
        w2t[n * LDW2 + k] = isbf ? ((const unsigned short*)W2)[idx]
                                 : f2b(((const float*)W2)[idx]);
    }
    {
        float s = 0.f;
        #pragma unroll
        for (int p = 0; p < NPART; ++p) s += statsP[p * 256 + tid];
        redu[tid] = s;
    }
    __syncthreads();
    if (tid < 128) {
        const float invn = 1.0f / (float)N_NODES;
        float mu = redu[tid] * invn;
        float var = redu[128 + tid] * invn - mu * mu;
        float rs = rsqrtf(var + BN_EPS);
        float g = ldf(gamma, tid, isbf);
        sc[tid] = rs * g;
        sh[tid] = ldf(beta, tid, isbf) - mu * rs * g;
    }
    __syncthreads();

    int lane = tid & 63;
    int wave = tid >> 6;
    int m0 = blockIdx.x * 64 + wave * 16;
    int lm = lane & 15;
    int quad = lane >> 4;

    int arow = m0 + lm;
    int arow_c = arow < N_NODES ? arow : 0;
    bf16x8 a[4];
    #pragma unroll
    for (int q = 0; q < 4; ++q) {
        uint4 gv = *(const uint4*)(agg1p + (size_t)arow_c * 64 + q * 16 + quad * 4);
        int kb = q * 32 + quad * 8;
        float2 f0 = up2(gv.x), f1 = up2(gv.y), f2 = up2(gv.z), f3 = up2(gv.w);
        float e0 = f0.x * sc[kb + 0] + sh[kb + 0];
        float e1 = f0.y * sc[kb + 1] + sh[kb + 1];
        float e2 = f1.x * sc[kb + 2] + sh[kb + 2];
        float e3 = f1.y * sc[kb + 3] + sh[kb + 3];
        float e4 = f2.x * sc[kb + 4] + sh[kb + 4];
        float e5 = f2.y * sc[kb + 5] + sh[kb + 5];
        float e6 = f3.x * sc[kb + 6] + sh[kb + 6];
        float e7 = f3.y * sc[kb + 7] + sh[kb + 7];
        bf16x8 t;
        t[0] = (short)f2b(e0 > 0.f ? e0 : 0.f);
        t[1] = (short)f2b(e1 > 0.f ? e1 : 0.f);
        t[2] = (short)f2b(e2 > 0.f ? e2 : 0.f);
        t[3] = (short)f2b(e3 > 0.f ? e3 : 0.f);
        t[4] = (short)f2b(e4 > 0.f ? e4 : 0.f);
        t[5] = (short)f2b(e5 > 0.f ? e5 : 0.f);
        t[6] = (short)f2b(e6 > 0.f ? e6 : 0.f);
        t[7] = (short)f2b(e7 > 0.f ? e7 : 0.f);
        a[q] = t;
    }

    float dsc[4];
    #pragma unroll
    for (int r = 0; r < 4; ++r) {
        int grow = m0 + quad * 4 + r;
        dsc[r] = (grow < N_NODES) ? rsqrtf((float)(counts[grow] + 1)) : 0.f;
    }

    #pragma unroll
    for (int nt = 0; nt < 4; ++nt) {
        int n0 = nt * 16;
        f32x4 acc = {0.f, 0.f, 0.f, 0.f};
        #pragma unroll
        for (int q = 0; q < 4; ++q) {
            bf16x8 b = *(const bf16x8*)(w2t + (n0 + lm) * LDW2 + q * 32 + quad * 8);
            acc = __builtin_amdgcn_mfma_f32_16x16x32_bf16(a[q], b, acc, 0, 0, 0);
        }
        float bias = ldf(b2, n0 + lm, isbf);
        #pragma unroll
        for (int r = 0; r < 4; ++r) {
            int grow = m0 + quad * 4 + r;
            if (grow <= N_NODES)          // row N_NODES -> zero row for prop2 padding
                g2[grow * DOUT + n0 + lm] = f2b(dsc[r] * (acc[r] + bias));
        }
    }
}

// ---------- propagate 2 + log_softmax: 32 lanes/node, 2 feats/lane, 16-deep, no tails ----------
__global__ __launch_bounds__(256) void k_prop2_lsm(const int* __restrict__ counts, const int* __restrict__ ej,
                                                   const unsigned int* __restrict__ g2p,   // [N+1][32] dwords
                                                   const void* __restrict__ W1, void* __restrict__ out) {
    __shared__ int sdet;
    int tid = threadIdx.x;
    DETECT_ISBF(W1, tid, sdet, isbf)

    int n = blockIdx.x * 8 + (tid >> 5);
    if (n >= N_NODES) return;
    int lane = tid & 31;
    int cnt = counts[n];
    int t = cnt < SLOT ? cnt : SLOT;
    int tp = (t + 15) & ~15; if (tp > SLOT) tp = SLOT;
    const int* ejn = ej + (size_t)n * SLOT;
    float2 v = up2(g2p[(size_t)n * 32 + lane]);
    float ax0 = v.x, ay0 = v.y, ax1 = 0.f, ay1 = 0.f;
    float ax2 = 0.f, ay2 = 0.f, ax3 = 0.f, ay3 = 0.f;
    for (int j = 0; j < tp; j += 16) {
        const int4* ej4 = (const int4*)(ejn + j);
        int4 E0 = ej4[0], E1 = ej4[1], E2 = ej4[2], E3 = ej4[3];
        int e[16] = {E0.x, E0.y, E0.z, E0.w, E1.x, E1.y, E1.z, E1.w,
                     E2.x, E2.y, E2.z, E2.w, E3.x, E3.y, E3.z, E3.w};
        unsigned int gg[16];
        #pragma unroll
        for (int q = 0; q < 16; ++q) gg[q] = g2p[(size_t)e[q] * 32 + lane];
        #pragma unroll
        for (int q = 0; q < 16; ++q) {
            float2 f = up2(gg[q]);
            if ((q & 3) == 0) { ax0 += f.x; ay0 += f.y; }
            else if ((q & 3) == 1) { ax1 += f.x; ay1 += f.y; }
            else if ((q & 3) == 2) { ax2 += f.x; ay2 += f.y; }
            else { ax3 += f.x; ay3 += f.y; }
        }
    }
    float dv = rsqrtf((float)(cnt + 1));
    float ax = dv * ((ax0 + ax1) + (ax2 + ax3));
    float ay = dv * ((ay0 + ay1) + (ay2 + ay3));
    float m = fmaxf(ax, ay);
    #pragma unroll
    for (int off = 16; off >= 1; off >>= 1) m = fmaxf(m, __shfl_xor(m, off, 32));
    float sum = __expf(ax - m) + __expf(ay - m);
    #pragma unroll
    for (int off = 16; off >= 1; off >>= 1) sum += __shfl_xor(sum, off, 32);
    float lse = m + __logf(sum);
    float rx = ax - lse, ry = ay - lse;
    if (isbf) {
        ((unsigned int*)out)[(size_t)n * 32 + lane] = pk2(rx, ry);
    } else {
        float2* o = (float2*)((float*)out + (size_t)n * 64 + 2 * lane);
        *o = make_float2(rx, ry);
    }
}

extern "C" void kernel_launch(void* const* d_in, const int* in_sizes, int n_in,
                              void* d_out, int out_size, void* d_ws, size_t ws_size,
                              hipStream_t stream) {
    const void* x     = d_in[0];
    const void* W1    = d_in[1];
    const void* b1    = d_in[2];
    const void* gamma = d_in[3];
    const void* beta  = d_in[4];
    const void* W2    = d_in[5];
    const void* b2    = d_in[6];
    const void* ei    = d_in[7];

    char* w = (char*)d_ws;
    float*          statsP = (float*)(w + 0);                  //     32,768 (NPART*256*4)
    int*            gcnt   = (int*)(w + 32768);                //      1,024 (196 used)
    int*            counts = (int*)(w + 33792);                //    200,000
    float*          disv   = (float*)(w + 233792);             //    200,016 ((N+1) floats, padded)
    int*            ej     = (int*)(w + 433808);               // 12,800,000 (N*SLOT*4)
    unsigned int*   bpk    = (unsigned int*)(w + 13233808);    //  3,813,376 (NBUK*BCAP*4)
    unsigned short* g1     = (unsigned short*)(w + 17047184);  // 12,800,256 ((N+1)*128*2)
    unsigned int*   agg1p  = (unsigned int*)(w + 29847440);    // 12,800,000
    unsigned short* g2     = (unsigned short*)(w + 42647440);  //  6,400,128 ((N+1)*64*2)
    // total ~49.0 MB

    hipMemsetAsync(w, 0, 33792, stream);   // statsP + gcnt

    k_binA<<<(NE + EPB - 1) / EPB, 256, 0, stream>>>(ei, gcnt, bpk);

    k_binB<<<NBUK, 256, 0, stream>>>(bpk, gcnt, counts, disv, ej);

    k_gemm1_mfma<<<(N_NODES + 63) / 64, 256, 0, stream>>>(x, W1, b1, g1);

    k_prop1<<<(N_NODES + 3) / 4, 256, 0, stream>>>(counts, disv, ej, (const unsigned int*)g1, agg1p, statsP);

    k_gemm2_mfma<<<(N_NODES + 63) / 64, 256, 0, stream>>>(agg1p, statsP, gamma, beta, W2, b2,
                                                          W1, counts, g2);

    k_prop2_lsm<<<(N_NODES + 7) / 8, 256, 0, stream>>>(counts, ej, (const unsigned int*)g2, W1, d_out);
}